// Round 1
// baseline (15496.701 us; speedup 1.0000x reference)
//
#include <hip/hip_runtime.h>
#include <hip/hip_bf16.h>

#define S_ 64
#define T_ 64
#define B_ 32
#define E_ 512
#define H_ 1024
#define V_ 32000
#define H3 3072
#define H2 2048
#define EH 1536

// ---------------- embedding gathers ----------------
__global__ void k_embed_src(const int* __restrict__ src, const float* __restrict__ emb,
                            float* __restrict__ out) {
    int row = blockIdx.x;              // s*B + b
    int tok = src[row];
    const float4* e = reinterpret_cast<const float4*>(emb + (size_t)tok * E_);
    float4* o = reinterpret_cast<float4*>(out + (size_t)row * E_);
    o[threadIdx.x] = e[threadIdx.x];   // 128 threads * float4 = 512
}

__global__ void k_embed_dec(const int* __restrict__ src, const int* __restrict__ trg,
                            const float* __restrict__ emb, float* __restrict__ out) {
    int row = blockIdx.x;              // t*B + b
    int t = row >> 5, b = row & 31;
    int tok = (t == 0) ? src[(S_ - 1) * B_ + b] : trg[(t - 1) * B_ + b];
    const float4* e = reinterpret_cast<const float4*>(emb + (size_t)tok * E_);
    float4* o = reinterpret_cast<float4*>(out + (size_t)row * E_);
    o[threadIdx.x] = e[threadIdx.x];
}

// ---------------- big tiled f32 GEMM:  C[n,m] = sum_k A[n,k]*B[m,k] + bias[m] ----------------
// A: [N, lda] row-major, B: [M, ldb] row-major (NT gemm). Tile 128x128, 256 thr, 8x8/thread.
// Requires N%128==0, M%128==0, K%16==0, all pointers 16B aligned.
__global__ __launch_bounds__(256) void k_gemm_nt(
    const float* __restrict__ A, int lda,
    const float* __restrict__ Bm, int ldb,
    const float* __restrict__ bias,
    float* __restrict__ C, int ldc, int K) {
    __shared__ float As[16][132];
    __shared__ float Bs[16][132];
    const int m0 = blockIdx.x * 128, n0 = blockIdx.y * 128;
    const int tid = threadIdx.x;
    const int tx = tid & 15, ty = tid >> 4;
    float acc[8][8] = {};
    for (int k0 = 0; k0 < K; k0 += 16) {
#pragma unroll
        for (int l = 0; l < 2; ++l) {
            int idx = tid + l * 256;               // 0..511
            int row = idx >> 2, k4 = (idx & 3) << 2;
            float4 av = *reinterpret_cast<const float4*>(A + (size_t)(n0 + row) * lda + k0 + k4);
            As[k4 + 0][row] = av.x; As[k4 + 1][row] = av.y;
            As[k4 + 2][row] = av.z; As[k4 + 3][row] = av.w;
            float4 bv = *reinterpret_cast<const float4*>(Bm + (size_t)(m0 + row) * ldb + k0 + k4);
            Bs[k4 + 0][row] = bv.x; Bs[k4 + 1][row] = bv.y;
            Bs[k4 + 2][row] = bv.z; Bs[k4 + 3][row] = bv.w;
        }
        __syncthreads();
#pragma unroll
        for (int k = 0; k < 16; ++k) {
            float a[8], b[8];
            *reinterpret_cast<float4*>(a)     = *reinterpret_cast<const float4*>(&As[k][ty * 8]);
            *reinterpret_cast<float4*>(a + 4) = *reinterpret_cast<const float4*>(&As[k][ty * 8 + 4]);
            *reinterpret_cast<float4*>(b)     = *reinterpret_cast<const float4*>(&Bs[k][tx * 8]);
            *reinterpret_cast<float4*>(b + 4) = *reinterpret_cast<const float4*>(&Bs[k][tx * 8 + 4]);
#pragma unroll
            for (int i = 0; i < 8; ++i)
#pragma unroll
                for (int j = 0; j < 8; ++j) acc[i][j] += a[i] * b[j];
        }
        __syncthreads();
    }
#pragma unroll
    for (int i = 0; i < 8; ++i) {
        int row = n0 + ty * 8 + i;
        float* Crow = C + (size_t)row * ldc + m0 + tx * 8;
#pragma unroll
        for (int j = 0; j < 8; ++j) {
            float bj = bias ? bias[m0 + tx * 8 + j] : 0.f;
            Crow[j] = acc[i][j] + bj;
        }
    }
}

// ---------------- small recurrent GEMM: C[32, M] = A[32,1024] * B[M,1024(ldb)]^T ----------------
// grid.x = M/32, grid.z selects operand set (for batching two independent GEMMs).
__global__ __launch_bounds__(256) void k_gemm_rnn(
    const float* __restrict__ A0, const float* __restrict__ B0, int ldb0, float* __restrict__ C0,
    const float* __restrict__ A1, const float* __restrict__ B1, int ldb1, float* __restrict__ C1,
    int M) {
    const float* A  = blockIdx.z ? A1 : A0;
    const float* Bw = blockIdx.z ? B1 : B0;
    float* C        = blockIdx.z ? C1 : C0;
    int ldb         = blockIdx.z ? ldb1 : ldb0;
    __shared__ float As[32][36];           // [k][row], padded for alignment/banks
    const int tid = threadIdx.x;
    const int col = tid & 31, g = tid >> 5;       // g=0..7 -> rows g*4..g*4+3
    const int m = blockIdx.x * 32 + col;
    float acc0 = 0.f, acc1 = 0.f, acc2 = 0.f, acc3 = 0.f;
    for (int k0 = 0; k0 < 1024; k0 += 32) {
        int lrow = tid >> 3, lk = (tid & 7) << 2;
        float4 av = *reinterpret_cast<const float4*>(A + lrow * 1024 + k0 + lk);
        As[lk + 0][lrow] = av.x; As[lk + 1][lrow] = av.y;
        As[lk + 2][lrow] = av.z; As[lk + 3][lrow] = av.w;
        float4 bq[8];
        const float4* Bp = reinterpret_cast<const float4*>(Bw + (size_t)m * ldb + k0);
#pragma unroll
        for (int q = 0; q < 8; ++q) bq[q] = Bp[q];
        __syncthreads();
#pragma unroll
        for (int kk = 0; kk < 32; ++kk) {
            float bval = reinterpret_cast<const float*>(bq)[kk];
            float4 a4 = *reinterpret_cast<const float4*>(&As[kk][g * 4]);
            acc0 += a4.x * bval; acc1 += a4.y * bval;
            acc2 += a4.z * bval; acc3 += a4.w * bval;
        }
        __syncthreads();
    }
    C[(size_t)(g * 4 + 0) * M + m] = acc0;
    C[(size_t)(g * 4 + 1) * M + m] = acc1;
    C[(size_t)(g * 4 + 2) * M + m] = acc2;
    C[(size_t)(g * 4 + 3) * M + m] = acc3;
}

// ---------------- attention scores: scores[b,s] = sum_j relu(hWa[b,j]+ep[b,s,j]) * v[j] ----------------
__global__ __launch_bounds__(256) void k_attn_scores(const float* __restrict__ hWa,
                                                     const float* __restrict__ ep,
                                                     const float* __restrict__ vv,
                                                     float* __restrict__ scores) {
    int bs = blockIdx.x;                   // b*64 + s
    int b = bs >> 6;
    int tid = threadIdx.x;
    float acc = 0.f;
#pragma unroll
    for (int l = 0; l < 4; ++l) {
        int j = tid + l * 256;
        float e = hWa[b * H_ + j] + ep[(size_t)bs * H_ + j];
        acc += fmaxf(e, 0.f) * vv[j];
    }
    for (int off = 32; off; off >>= 1) acc += __shfl_down(acc, off);
    __shared__ float ps[4];
    if ((tid & 63) == 0) ps[tid >> 6] = acc;
    __syncthreads();
    if (tid == 0) scores[bs] = ps[0] + ps[1] + ps[2] + ps[3];
}

// ---------------- softmax over S + context: ctx[b,:] = softmax(scores[b,:]) @ enc[b,:,:] ----------------
__global__ __launch_bounds__(256) void k_softmax_ctx(const float* __restrict__ scores,
                                                     const float* __restrict__ enc,
                                                     float* __restrict__ ctx) {
    int b = blockIdx.x, tid = threadIdx.x;
    __shared__ float al[64];
    if (tid < 64) al[tid] = scores[b * 64 + tid];
    __syncthreads();
    float m = -1e30f;
    for (int s = 0; s < 64; ++s) m = fmaxf(m, al[s]);
    float sum = 0.f;
    for (int s = 0; s < 64; ++s) sum += expf(al[s] - m);
    float inv = 1.f / sum;
    __syncthreads();
    if (tid < 64) al[tid] = expf(al[tid] - m) * inv;
    __syncthreads();
#pragma unroll
    for (int l = 0; l < 4; ++l) {
        int j = tid + l * 256;
        float c = 0.f;
        for (int s = 0; s < 64; ++s) c += al[s] * enc[((size_t)b * 64 + s) * H_ + j];
        ctx[b * H_ + j] = c;
    }
}

// ---------------- encoder GRU gates (both directions) ----------------
__global__ __launch_bounds__(256) void k_enc_gates(
    const float* __restrict__ gi_f, const float* __restrict__ gi_b,
    const float* __restrict__ gh_f, const float* __restrict__ gh_b,
    const float* __restrict__ bhh_f, const float* __restrict__ bhh_b,
    float* __restrict__ h_f, float* __restrict__ h_b,
    float* __restrict__ enc, int step) {
    int dir = blockIdx.x >> 7;                                 // 128 blocks / dir
    int bi = ((blockIdx.x & 127) << 8) + threadIdx.x;          // 0..32767
    int b = bi >> 10, j = bi & 1023;
    int s = dir ? (63 - step) : step;
    const float* gi  = dir ? gi_b : gi_f;
    const float* gh  = dir ? gh_b : gh_f;
    const float* bhh = dir ? bhh_b : bhh_f;
    float* h = dir ? h_b : h_f;
    size_t gro = (size_t)(s * B_ + b) * H3 + j;
    float gir = gi[gro], giz = gi[gro + H_], gin = gi[gro + 2 * H_];
    size_t gho = (size_t)b * H3 + j;
    float ghr = gh[gho] + bhh[j];
    float ghz = gh[gho + H_] + bhh[H_ + j];
    float ghn = gh[gho + 2 * H_] + bhh[2 * H_ + j];
    float r = 1.f / (1.f + expf(-(gir + ghr)));
    float z = 1.f / (1.f + expf(-(giz + ghz)));
    float n = tanhf(gin + r * ghn);
    float hold = h[bi];
    float hnew = (1.f - z) * n + z * hold;
    h[bi] = hnew;
    enc[((size_t)b * 64 + s) * H_ + j] += hnew;   // fwd writes pos i, bwd pos 63-i; enc zero-inited
}

// ---------------- decoder GRU gates + state store ----------------
__global__ __launch_bounds__(256) void k_dec_gates(
    const float* __restrict__ gi_e, const float* __restrict__ gic,
    const float* __restrict__ ghd, const float* __restrict__ bhh_d,
    const float* __restrict__ ctx, float* __restrict__ h_d,
    float* __restrict__ states, int t) {
    int bi = blockIdx.x * 256 + threadIdx.x;
    int b = bi >> 10, j = bi & 1023;
    size_t ge = (size_t)(t * B_ + b) * H3 + j;
    size_t gc = (size_t)b * H3 + j;
    float gir = gi_e[ge] + gic[gc];
    float giz = gi_e[ge + H_] + gic[gc + H_];
    float gin = gi_e[ge + 2 * H_] + gic[gc + 2 * H_];
    float ghr = ghd[gc] + bhh_d[j];
    float ghz = ghd[gc + H_] + bhh_d[H_ + j];
    float ghn = ghd[gc + 2 * H_] + bhh_d[2 * H_ + j];
    float r = 1.f / (1.f + expf(-(gir + ghr)));
    float z = 1.f / (1.f + expf(-(giz + ghz)));
    float n = tanhf(gin + r * ghn);
    float hold = h_d[bi];
    float hnew = (1.f - z) * n + z * hold;
    h_d[bi] = hnew;
    size_t so = (size_t)(t * B_ + b) * H2;
    states[so + j] = hnew;
    states[so + H_ + j] = ctx[bi];
}

extern "C" void kernel_launch(void* const* d_in, const int* in_sizes, int n_in,
                              void* d_out, int out_size, void* d_ws, size_t ws_size,
                              hipStream_t stream) {
    const int*   src   = (const int*)d_in[0];
    const int*   trg   = (const int*)d_in[1];
    const float* emb   = (const float*)d_in[2];
    const float* Wih_f = (const float*)d_in[3];
    const float* Whh_f = (const float*)d_in[4];
    const float* bih_f = (const float*)d_in[5];
    const float* bhh_f = (const float*)d_in[6];
    const float* Wih_b = (const float*)d_in[7];
    const float* Whh_b = (const float*)d_in[8];
    const float* bih_b = (const float*)d_in[9];
    const float* bhh_b = (const float*)d_in[10];
    const float* Wa    = (const float*)d_in[11];
    const float* ba    = (const float*)d_in[12];
    const float* vv    = (const float*)d_in[13];
    const float* Wih_d = (const float*)d_in[14];
    const float* Whh_d = (const float*)d_in[15];
    const float* bih_d = (const float*)d_in[16];
    const float* bhh_d = (const float*)d_in[17];
    const float* Wout  = (const float*)d_in[18];
    const float* bout  = (const float*)d_in[19];
    float* out = (float*)d_out;

    float* w = (float*)d_ws;
    size_t o = 0;
    auto alloc = [&](size_t n) { float* p = w + o; o += n; return p; };
    float* src_emb = alloc((size_t)S_ * B_ * E_);
    float* dec_emb = alloc((size_t)T_ * B_ * E_);
    float* gi_f    = alloc((size_t)S_ * B_ * H3);   // reused as gi_e after encoder
    float* gi_b    = alloc((size_t)S_ * B_ * H3);   // reused as states after encoder
    float* enc     = alloc((size_t)B_ * S_ * H_);   // [B,S,H]
    float* ep      = alloc((size_t)B_ * S_ * H_);   // enc_part (attention precompute)
    float* h_f     = alloc(B_ * H_);
    float* h_b     = alloc(B_ * H_);
    float* h_d     = alloc(B_ * H_);
    float* gh_f    = alloc(B_ * H3);
    float* gh_b    = alloc(B_ * H3);
    float* hWa     = alloc(B_ * H_);
    float* scores  = alloc(B_ * S_);
    float* ctx     = alloc(B_ * H_);
    float* gic     = alloc(B_ * H3);
    float* ghd     = alloc(B_ * H3);
    float* gi_e   = gi_f;
    float* states = gi_b;
    (void)ws_size; (void)in_sizes; (void)n_in; (void)out_size;

    hipMemsetAsync(enc, 0, (size_t)B_ * S_ * H_ * sizeof(float), stream);
    hipMemsetAsync(h_f, 0, (size_t)B_ * H_ * sizeof(float), stream);
    hipMemsetAsync(h_b, 0, (size_t)B_ * H_ * sizeof(float), stream);

    k_embed_src<<<S_ * B_, 128, 0, stream>>>(src, emb, src_emb);
    k_embed_dec<<<T_ * B_, 128, 0, stream>>>(src, trg, emb, dec_emb);

    // input projections for encoder (all timesteps at once)
    k_gemm_nt<<<dim3(H3 / 128, (S_ * B_) / 128), 256, 0, stream>>>(
        src_emb, E_, Wih_f, E_, bih_f, gi_f, H3, E_);
    k_gemm_nt<<<dim3(H3 / 128, (S_ * B_) / 128), 256, 0, stream>>>(
        src_emb, E_, Wih_b, E_, bih_b, gi_b, H3, E_);

    // encoder: 64 sequential steps, fwd+bwd batched via grid.z
    for (int i = 0; i < 64; ++i) {
        k_gemm_rnn<<<dim3(H3 / 32, 1, 2), 256, 0, stream>>>(
            h_f, Whh_f, H_, gh_f, h_b, Whh_b, H_, gh_b, H3);
        k_enc_gates<<<256, 256, 0, stream>>>(gi_f, gi_b, gh_f, gh_b, bhh_f, bhh_b,
                                             h_f, h_b, enc, i);
    }

    // attention enc-side precompute: ep = enc @ Wa[:,H:]^T + ba
    k_gemm_nt<<<dim3(H_ / 128, (B_ * S_) / 128), 256, 0, stream>>>(
        enc, H_, Wa + H_, H2, ba, ep, H_, H_);
    // decoder input projection (embedding part): gi_e = dec_emb @ Wih_d[:,:E]^T + bih_d
    k_gemm_nt<<<dim3(H3 / 128, (T_ * B_) / 128), 256, 0, stream>>>(
        dec_emb, E_, Wih_d, EH, bih_d, gi_e, H3, E_);

    hipMemcpyAsync(h_d, h_f, (size_t)B_ * H_ * sizeof(float),
                   hipMemcpyDeviceToDevice, stream);

    // decoder: 64 sequential steps (logits deferred)
    for (int t = 0; t < 64; ++t) {
        k_gemm_rnn<<<dim3(H_ / 32, 1, 1), 256, 0, stream>>>(
            h_d, Wa, H2, hWa, nullptr, nullptr, 0, nullptr, H_);
        k_attn_scores<<<B_ * S_, 256, 0, stream>>>(hWa, ep, vv, scores);
        k_softmax_ctx<<<B_, 256, 0, stream>>>(scores, enc, ctx);
        k_gemm_rnn<<<dim3(H3 / 32, 1, 2), 256, 0, stream>>>(
            ctx, Wih_d + E_, EH, gic, h_d, Whh_d, H_, ghd, H3);
        k_dec_gates<<<128, 256, 0, stream>>>(gi_e, gic, ghd, bhh_d, ctx, h_d, states, t);
    }

    // deferred output head: out = states @ Wout^T + bout   (268 GFLOP, Wout read once)
    k_gemm_nt<<<dim3(V_ / 128, (T_ * B_) / 128), 256, 0, stream>>>(
        states, H2, Wout, H2, bout, out, V_, H2);
}

// Round 2
// 12285.217 us; speedup vs baseline: 1.2614x; 1.2614x over previous
//
#include <hip/hip_runtime.h>
#include <hip/hip_bf16.h>

#define S_ 64
#define T_ 64
#define B_ 32
#define E_ 512
#define H_ 1024
#define V_ 32000
#define H3 3072
#define H2 2048
#define EH 1536

typedef unsigned short u16;
typedef unsigned int u32;
typedef __attribute__((ext_vector_type(8))) short bf16x8;
typedef __attribute__((ext_vector_type(4))) float f32x4;

// ---------------- embedding gathers (f32) ----------------
__global__ void k_embed_src(const int* __restrict__ src, const float* __restrict__ emb,
                            float* __restrict__ out) {
    int row = blockIdx.x;              // s*B + b
    int tok = src[row];
    const float4* e = reinterpret_cast<const float4*>(emb + (size_t)tok * E_);
    float4* o = reinterpret_cast<float4*>(out + (size_t)row * E_);
    o[threadIdx.x] = e[threadIdx.x];   // 128 threads * float4 = 512
}

__global__ void k_embed_dec(const int* __restrict__ src, const int* __restrict__ trg,
                            const float* __restrict__ emb, float* __restrict__ out) {
    int row = blockIdx.x;              // t*B + b
    int t = row >> 5, b = row & 31;
    int tok = (t == 0) ? src[(S_ - 1) * B_ + b] : trg[(t - 1) * B_ + b];
    const float4* e = reinterpret_cast<const float4*>(emb + (size_t)tok * E_);
    float4* o = reinterpret_cast<float4*>(out + (size_t)row * E_);
    o[threadIdx.x] = e[threadIdx.x];
}

// ---------------- f32 -> bf16 hi/lo split (pseudo-f32 decomposition) ----------------
__device__ __forceinline__ void splitf(float x, u16& h, u16& l) {
    u32 xb = __float_as_uint(x);
    u32 hb = (xb + 0x7FFFu + ((xb >> 16) & 1u)) & 0xFFFF0000u;  // RNE to bf16, kept in f32 form
    h = (u16)(hb >> 16);
    float lf = x - __uint_as_float(hb);                          // exact residual
    u32 lb = __float_as_uint(lf);
    l = (u16)((lb + 0x7FFFu + ((lb >> 16) & 1u)) >> 16);
}

// in: [rows][ld] f32 (rows = gridDim.y), out hi/lo: [rows][cols4*4] bf16 compact
__global__ __launch_bounds__(256) void k_split(const float* __restrict__ in, int ld, int cols4,
                                               u16* __restrict__ hi, u16* __restrict__ lo) {
    int c4 = blockIdx.x * 256 + threadIdx.x;
    if (c4 >= cols4) return;
    size_t r = blockIdx.y;
    float4 v = *reinterpret_cast<const float4*>(in + r * ld + (size_t)c4 * 4);
    ushort4 h, l;
    splitf(v.x, h.x, l.x); splitf(v.y, h.y, l.y);
    splitf(v.z, h.z, l.z); splitf(v.w, h.w, l.w);
    size_t o = (r * cols4 + c4) * 4;
    *reinterpret_cast<ushort4*>(hi + o) = h;
    *reinterpret_cast<ushort4*>(lo + o) = l;
}

// ---------------- split-bf16 MFMA GEMM: C = Ah*Bh^T + Ah*Bl^T + Al*Bh^T + bias ----------------
// A*: [M][K] bf16, B*: [N][K] bf16 (NT), C: [M][ldc] f32. M%128==0, Ncols%128==0, K%32==0.
// 128x128 tile, 4 waves (2x2), each wave 64x64 via 4x4 frags of mfma_f32_16x16x32_bf16.
__device__ __forceinline__ void load_lds16(const void* g, void* l) {
    __builtin_amdgcn_global_load_lds((const __attribute__((address_space(1))) u32*)g,
                                     (__attribute__((address_space(3))) u32*)l, 16, 0, 0);
}

__global__ __launch_bounds__(256, 2) void k_gemm_mfma3(
    const u16* __restrict__ Ah, const u16* __restrict__ Al,
    const u16* __restrict__ Bh, const u16* __restrict__ Bl,
    const float* __restrict__ bias, float* __restrict__ C,
    int ldc, int K)
{
    __shared__ u16 ls[4][128 * 32];        // Ah, Al, Bh, Bl tiles: [128 rows][32 k] bf16
    const int tid = threadIdx.x;
    const int lane = tid & 63, w = tid >> 6;
    const int wr = w >> 1, wc = w & 1;
    const size_t m0 = (size_t)blockIdx.x * 128, n0 = (size_t)blockIdx.y * 128;

    // staging: chunk c = (w*2+i)*64 + lane (i=0,1); 16B chunk -> row=c>>2, k-chunk=(c&3)*8
    const int c0 = (w * 2) * 64 + lane;
    const int r0 = c0 >> 2, kc0 = (c0 & 3) << 3;
    const size_t rstep = (size_t)16 * K;   // chunk1 is row+16
    const u16* gAh = Ah + (m0 + r0) * K + kc0;
    const u16* gAl = Al + (m0 + r0) * K + kc0;
    const u16* gBh = Bh + (n0 + r0) * K + kc0;
    const u16* gBl = Bl + (n0 + r0) * K + kc0;
    const int lo0 = c0 * 8;                // u16 offset in LDS tile

    // fragment read coords: A[row=lane&15][k=(lane>>4)*8 ..+7]
    const int frow = lane & 15, fk = (lane >> 4) << 3;
    const int offA = (wr * 64 + frow) * 32 + fk;
    const int offB = (wc * 64 + frow) * 32 + fk;

    f32x4 acc[4][4] = {};

    for (int k0 = 0; k0 < K; k0 += 32) {
        load_lds16(gAh + k0, &ls[0][lo0]);
        load_lds16(gAh + rstep + k0, &ls[0][lo0 + 512]);
        load_lds16(gAl + k0, &ls[1][lo0]);
        load_lds16(gAl + rstep + k0, &ls[1][lo0 + 512]);
        load_lds16(gBh + k0, &ls[2][lo0]);
        load_lds16(gBh + rstep + k0, &ls[2][lo0 + 512]);
        load_lds16(gBl + k0, &ls[3][lo0]);
        load_lds16(gBl + rstep + k0, &ls[3][lo0 + 512]);
        __syncthreads();   // drains vmcnt (global_load_lds) before reads

        bf16x8 fAh[4], fAl[4], fBh[4], fBl[4];
#pragma unroll
        for (int m = 0; m < 4; ++m) {
            fAh[m] = *reinterpret_cast<const bf16x8*>(&ls[0][offA + m * 512]);
            fAl[m] = *reinterpret_cast<const bf16x8*>(&ls[1][offA + m * 512]);
        }
#pragma unroll
        for (int n = 0; n < 4; ++n) {
            fBh[n] = *reinterpret_cast<const bf16x8*>(&ls[2][offB + n * 512]);
            fBl[n] = *reinterpret_cast<const bf16x8*>(&ls[3][offB + n * 512]);
        }
#pragma unroll
        for (int m = 0; m < 4; ++m)
#pragma unroll
            for (int n = 0; n < 4; ++n) {
                acc[m][n] = __builtin_amdgcn_mfma_f32_16x16x32_bf16(fAl[m], fBh[n], acc[m][n], 0, 0, 0);
                acc[m][n] = __builtin_amdgcn_mfma_f32_16x16x32_bf16(fAh[m], fBl[n], acc[m][n], 0, 0, 0);
                acc[m][n] = __builtin_amdgcn_mfma_f32_16x16x32_bf16(fAh[m], fBh[n], acc[m][n], 0, 0, 0);
            }
        __syncthreads();   // all reads done before next stage overwrites LDS
    }

    // C/D layout (verified m89/m91): col = lane&15, row = (lane>>4)*4 + reg
    const int crow0 = wr * 64 + ((lane >> 4) << 2);
    const int ccol0 = wc * 64 + (lane & 15);
#pragma unroll
    for (int n = 0; n < 4; ++n) {
        const size_t col = n0 + ccol0 + n * 16;
        const float bv = bias ? bias[col] : 0.f;
#pragma unroll
        for (int m = 0; m < 4; ++m)
#pragma unroll
            for (int r = 0; r < 4; ++r)
                C[(m0 + crow0 + m * 16 + r) * (size_t)ldc + col] = acc[m][n][r] + bv;
    }
}

// ---------------- f32 tiled GEMM (fallback only) ----------------
__global__ __launch_bounds__(256) void k_gemm_nt(
    const float* __restrict__ A, int lda,
    const float* __restrict__ Bm, int ldb,
    const float* __restrict__ bias,
    float* __restrict__ C, int ldc, int K) {
    __shared__ float As[16][132];
    __shared__ float Bs[16][132];
    const int m0 = blockIdx.x * 128, n0 = blockIdx.y * 128;
    const int tid = threadIdx.x;
    const int tx = tid & 15, ty = tid >> 4;
    float acc[8][8] = {};
    for (int k0 = 0; k0 < K; k0 += 16) {
#pragma unroll
        for (int l = 0; l < 2; ++l) {
            int idx = tid + l * 256;
            int row = idx >> 2, k4 = (idx & 3) << 2;
            float4 av = *reinterpret_cast<const float4*>(A + (size_t)(n0 + row) * lda + k0 + k4);
            As[k4 + 0][row] = av.x; As[k4 + 1][row] = av.y;
            As[k4 + 2][row] = av.z; As[k4 + 3][row] = av.w;
            float4 bv = *reinterpret_cast<const float4*>(Bm + (size_t)(m0 + row) * ldb + k0 + k4);
            Bs[k4 + 0][row] = bv.x; Bs[k4 + 1][row] = bv.y;
            Bs[k4 + 2][row] = bv.z; Bs[k4 + 3][row] = bv.w;
        }
        __syncthreads();
#pragma unroll
        for (int k = 0; k < 16; ++k) {
            float a[8], b[8];
            *reinterpret_cast<float4*>(a)     = *reinterpret_cast<const float4*>(&As[k][ty * 8]);
            *reinterpret_cast<float4*>(a + 4) = *reinterpret_cast<const float4*>(&As[k][ty * 8 + 4]);
            *reinterpret_cast<float4*>(b)     = *reinterpret_cast<const float4*>(&Bs[k][tx * 8]);
            *reinterpret_cast<float4*>(b + 4) = *reinterpret_cast<const float4*>(&Bs[k][tx * 8 + 4]);
#pragma unroll
            for (int i = 0; i < 8; ++i)
#pragma unroll
                for (int j = 0; j < 8; ++j) acc[i][j] += a[i] * b[j];
        }
        __syncthreads();
    }
#pragma unroll
    for (int i = 0; i < 8; ++i) {
        int row = n0 + ty * 8 + i;
        float* Crow = C + (size_t)row * ldc + m0 + tx * 8;
#pragma unroll
        for (int j = 0; j < 8; ++j) {
            float bj = bias ? bias[m0 + tx * 8 + j] : 0.f;
            Crow[j] = acc[i][j] + bj;
        }
    }
}

// ---------------- small recurrent GEMM: C[32, M] = A[32,1024] * B[M,ldb]^T ----------------
__global__ __launch_bounds__(256) void k_gemm_rnn(
    const float* __restrict__ A0, const float* __restrict__ B0, int ldb0, float* __restrict__ C0,
    const float* __restrict__ A1, const float* __restrict__ B1, int ldb1, float* __restrict__ C1,
    int M) {
    const float* A  = blockIdx.z ? A1 : A0;
    const float* Bw = blockIdx.z ? B1 : B0;
    float* C        = blockIdx.z ? C1 : C0;
    int ldb         = blockIdx.z ? ldb1 : ldb0;
    __shared__ float As[32][36];
    const int tid = threadIdx.x;
    const int col = tid & 31, g = tid >> 5;
    const int m = blockIdx.x * 32 + col;
    float acc0 = 0.f, acc1 = 0.f, acc2 = 0.f, acc3 = 0.f;
    for (int k0 = 0; k0 < 1024; k0 += 32) {
        int lrow = tid >> 3, lk = (tid & 7) << 2;
        float4 av = *reinterpret_cast<const float4*>(A + lrow * 1024 + k0 + lk);
        As[lk + 0][lrow] = av.x; As[lk + 1][lrow] = av.y;
        As[lk + 2][lrow] = av.z; As[lk + 3][lrow] = av.w;
        float4 bq[8];
        const float4* Bp = reinterpret_cast<const float4*>(Bw + (size_t)m * ldb + k0);
#pragma unroll
        for (int q = 0; q < 8; ++q) bq[q] = Bp[q];
        __syncthreads();
#pragma unroll
        for (int kk = 0; kk < 32; ++kk) {
            float bval = reinterpret_cast<const float*>(bq)[kk];
            float4 a4 = *reinterpret_cast<const float4*>(&As[kk][g * 4]);
            acc0 += a4.x * bval; acc1 += a4.y * bval;
            acc2 += a4.z * bval; acc3 += a4.w * bval;
        }
        __syncthreads();
    }
    C[(size_t)(g * 4 + 0) * M + m] = acc0;
    C[(size_t)(g * 4 + 1) * M + m] = acc1;
    C[(size_t)(g * 4 + 2) * M + m] = acc2;
    C[(size_t)(g * 4 + 3) * M + m] = acc3;
}

// ---------------- attention scores ----------------
__global__ __launch_bounds__(256) void k_attn_scores(const float* __restrict__ hWa,
                                                     const float* __restrict__ ep,
                                                     const float* __restrict__ vv,
                                                     float* __restrict__ scores) {
    int bs = blockIdx.x;
    int b = bs >> 6;
    int tid = threadIdx.x;
    float acc = 0.f;
#pragma unroll
    for (int l = 0; l < 4; ++l) {
        int j = tid + l * 256;
        float e = hWa[b * H_ + j] + ep[(size_t)bs * H_ + j];
        acc += fmaxf(e, 0.f) * vv[j];
    }
    for (int off = 32; off; off >>= 1) acc += __shfl_down(acc, off);
    __shared__ float ps[4];
    if ((tid & 63) == 0) ps[tid >> 6] = acc;
    __syncthreads();
    if (tid == 0) scores[bs] = ps[0] + ps[1] + ps[2] + ps[3];
}

// ---------------- softmax + context ----------------
__global__ __launch_bounds__(256) void k_softmax_ctx(const float* __restrict__ scores,
                                                     const float* __restrict__ enc,
                                                     float* __restrict__ ctx) {
    int b = blockIdx.x, tid = threadIdx.x;
    __shared__ float al[64];
    if (tid < 64) al[tid] = scores[b * 64 + tid];
    __syncthreads();
    float m = -1e30f;
    for (int s = 0; s < 64; ++s) m = fmaxf(m, al[s]);
    float sum = 0.f;
    for (int s = 0; s < 64; ++s) sum += expf(al[s] - m);
    float inv = 1.f / sum;
    __syncthreads();
    if (tid < 64) al[tid] = expf(al[tid] - m) * inv;
    __syncthreads();
#pragma unroll
    for (int l = 0; l < 4; ++l) {
        int j = tid + l * 256;
        float c = 0.f;
        for (int s = 0; s < 64; ++s) c += al[s] * enc[((size_t)b * 64 + s) * H_ + j];
        ctx[b * H_ + j] = c;
    }
}

// ---------------- encoder GRU gates ----------------
__global__ __launch_bounds__(256) void k_enc_gates(
    const float* __restrict__ gi_f, const float* __restrict__ gi_b,
    const float* __restrict__ gh_f, const float* __restrict__ gh_b,
    const float* __restrict__ bhh_f, const float* __restrict__ bhh_b,
    float* __restrict__ h_f, float* __restrict__ h_b,
    float* __restrict__ enc, int step) {
    int dir = blockIdx.x >> 7;
    int bi = ((blockIdx.x & 127) << 8) + threadIdx.x;
    int b = bi >> 10, j = bi & 1023;
    int s = dir ? (63 - step) : step;
    const float* gi  = dir ? gi_b : gi_f;
    const float* gh  = dir ? gh_b : gh_f;
    const float* bhh = dir ? bhh_b : bhh_f;
    float* h = dir ? h_b : h_f;
    size_t gro = (size_t)(s * B_ + b) * H3 + j;
    float gir = gi[gro], giz = gi[gro + H_], gin = gi[gro + 2 * H_];
    size_t gho = (size_t)b * H3 + j;
    float ghr = gh[gho] + bhh[j];
    float ghz = gh[gho + H_] + bhh[H_ + j];
    float ghn = gh[gho + 2 * H_] + bhh[2 * H_ + j];
    float r = 1.f / (1.f + expf(-(gir + ghr)));
    float z = 1.f / (1.f + expf(-(giz + ghz)));
    float n = tanhf(gin + r * ghn);
    float hold = h[bi];
    float hnew = (1.f - z) * n + z * hold;
    h[bi] = hnew;
    enc[((size_t)b * 64 + s) * H_ + j] += hnew;
}

// ---------------- decoder GRU gates + state store ----------------
__global__ __launch_bounds__(256) void k_dec_gates(
    const float* __restrict__ gi_e, const float* __restrict__ gic,
    const float* __restrict__ ghd, const float* __restrict__ bhh_d,
    const float* __restrict__ ctx, float* __restrict__ h_d,
    float* __restrict__ states, int t) {
    int bi = blockIdx.x * 256 + threadIdx.x;
    int b = bi >> 10, j = bi & 1023;
    size_t ge = (size_t)(t * B_ + b) * H3 + j;
    size_t gc = (size_t)b * H3 + j;
    float gir = gi_e[ge] + gic[gc];
    float giz = gi_e[ge + H_] + gic[gc + H_];
    float gin = gi_e[ge + 2 * H_] + gic[gc + 2 * H_];
    float ghr = ghd[gc] + bhh_d[j];
    float ghz = ghd[gc + H_] + bhh_d[H_ + j];
    float ghn = ghd[gc + 2 * H_] + bhh_d[2 * H_ + j];
    float r = 1.f / (1.f + expf(-(gir + ghr)));
    float z = 1.f / (1.f + expf(-(giz + ghz)));
    float n = tanhf(gin + r * ghn);
    float hold = h_d[bi];
    float hnew = (1.f - z) * n + z * hold;
    h_d[bi] = hnew;
    size_t so = (size_t)(t * B_ + b) * H2;
    states[so + j] = hnew;
    states[so + H_ + j] = ctx[bi];
}

extern "C" void kernel_launch(void* const* d_in, const int* in_sizes, int n_in,
                              void* d_out, int out_size, void* d_ws, size_t ws_size,
                              hipStream_t stream) {
    const int*   src   = (const int*)d_in[0];
    const int*   trg   = (const int*)d_in[1];
    const float* emb   = (const float*)d_in[2];
    const float* Wih_f = (const float*)d_in[3];
    const float* Whh_f = (const float*)d_in[4];
    const float* bih_f = (const float*)d_in[5];
    const float* bhh_f = (const float*)d_in[6];
    const float* Wih_b = (const float*)d_in[7];
    const float* Whh_b = (const float*)d_in[8];
    const float* bih_b = (const float*)d_in[9];
    const float* bhh_b = (const float*)d_in[10];
    const float* Wa    = (const float*)d_in[11];
    const float* ba    = (const float*)d_in[12];
    const float* vv    = (const float*)d_in[13];
    const float* Wih_d = (const float*)d_in[14];
    const float* Whh_d = (const float*)d_in[15];
    const float* bih_d = (const float*)d_in[16];
    const float* bhh_d = (const float*)d_in[17];
    const float* Wout  = (const float*)d_in[18];
    const float* bout  = (const float*)d_in[19];
    float* out = (float*)d_out;
    (void)in_sizes; (void)n_in; (void)out_size;

    float* w = (float*)d_ws;
    size_t o = 0;
    auto alloc = [&](size_t n) { float* p = w + o; o += n; return p; };
    float* src_emb = alloc((size_t)S_ * B_ * E_);
    float* dec_emb = alloc((size_t)T_ * B_ * E_);
    float* gi_f    = alloc((size_t)S_ * B_ * H3);   // reused as gi_e
    float* gi_b    = alloc((size_t)S_ * B_ * H3);   // reused as states
    float* enc     = alloc((size_t)B_ * S_ * H_);
    float* ep      = alloc((size_t)B_ * S_ * H_);
    float* h_f     = alloc(B_ * H_);
    float* h_b     = alloc(B_ * H_);
    float* h_d     = alloc(B_ * H_);
    float* gh_f    = alloc(B_ * H3);
    float* gh_b    = alloc(B_ * H3);
    float* hWa     = alloc(B_ * H_);
    float* scores  = alloc(B_ * S_);
    float* ctx     = alloc(B_ * H_);
    float* gic     = alloc(B_ * H3);
    float* ghd     = alloc(B_ * H3);
    float* gi_e   = gi_f;
    float* states = gi_b;

    // bf16 hi/lo region (MFMA path)
    u16* wu = (u16*)(w + o);
    size_t ou = 0;
    auto alloc16 = [&](size_t n) { u16* p = wu + ou; ou += n; return p; };
    u16* semb_h = alloc16((size_t)S_ * B_ * E_);  u16* semb_l = alloc16((size_t)S_ * B_ * E_);
    u16* demb_h = alloc16((size_t)T_ * B_ * E_);  u16* demb_l = alloc16((size_t)T_ * B_ * E_);
    u16* wihf_h = alloc16((size_t)H3 * E_);       u16* wihf_l = alloc16((size_t)H3 * E_);
    u16* wihb_h = alloc16((size_t)H3 * E_);       u16* wihb_l = alloc16((size_t)H3 * E_);
    u16* wihd_h = alloc16((size_t)H3 * E_);       u16* wihd_l = alloc16((size_t)H3 * E_);
    u16* wae_h  = alloc16((size_t)H_ * H_);       u16* wae_l  = alloc16((size_t)H_ * H_);
    u16* enc_h  = alloc16((size_t)B_ * S_ * H_);  u16* enc_l  = alloc16((size_t)B_ * S_ * H_);
    u16* st_h   = alloc16((size_t)T_ * B_ * H2);  u16* st_l   = alloc16((size_t)T_ * B_ * H2);
    u16* wout_h = alloc16((size_t)16000 * H2);    u16* wout_l = alloc16((size_t)16000 * H2);
    const bool mf = (o * 4 + ou * 2) <= ws_size;   // fall back to f32 GEMMs if ws too small

    hipMemsetAsync(enc, 0, (size_t)B_ * S_ * H_ * sizeof(float), stream);
    hipMemsetAsync(h_f, 0, (size_t)B_ * H_ * sizeof(float), stream);
    hipMemsetAsync(h_b, 0, (size_t)B_ * H_ * sizeof(float), stream);

    k_embed_src<<<S_ * B_, 128, 0, stream>>>(src, emb, src_emb);
    k_embed_dec<<<T_ * B_, 128, 0, stream>>>(src, trg, emb, dec_emb);

    // encoder input projections
    if (mf) {
        k_split<<<dim3(1, S_ * B_), 256, 0, stream>>>(src_emb, E_, E_ / 4, semb_h, semb_l);
        k_split<<<dim3(1, T_ * B_), 256, 0, stream>>>(dec_emb, E_, E_ / 4, demb_h, demb_l);
        k_split<<<dim3(1, H3), 256, 0, stream>>>(Wih_f, E_, E_ / 4, wihf_h, wihf_l);
        k_split<<<dim3(1, H3), 256, 0, stream>>>(Wih_b, E_, E_ / 4, wihb_h, wihb_l);
        k_split<<<dim3(1, H3), 256, 0, stream>>>(Wih_d, EH, E_ / 4, wihd_h, wihd_l);     // Wih_d[:, :E]
        k_split<<<dim3(1, H_), 256, 0, stream>>>(Wa + H_, H2, H_ / 4, wae_h, wae_l);     // Wa[:, H:]
        k_gemm_mfma3<<<dim3(16, H3 / 128), 256, 0, stream>>>(semb_h, semb_l, wihf_h, wihf_l,
                                                             bih_f, gi_f, H3, E_);
        k_gemm_mfma3<<<dim3(16, H3 / 128), 256, 0, stream>>>(semb_h, semb_l, wihb_h, wihb_l,
                                                             bih_b, gi_b, H3, E_);
    } else {
        k_gemm_nt<<<dim3(H3 / 128, (S_ * B_) / 128), 256, 0, stream>>>(
            src_emb, E_, Wih_f, E_, bih_f, gi_f, H3, E_);
        k_gemm_nt<<<dim3(H3 / 128, (S_ * B_) / 128), 256, 0, stream>>>(
            src_emb, E_, Wih_b, E_, bih_b, gi_b, H3, E_);
    }

    // encoder: 64 sequential steps
    for (int i = 0; i < 64; ++i) {
        k_gemm_rnn<<<dim3(H3 / 32, 1, 2), 256, 0, stream>>>(
            h_f, Whh_f, H_, gh_f, h_b, Whh_b, H_, gh_b, H3);
        k_enc_gates<<<256, 256, 0, stream>>>(gi_f, gi_b, gh_f, gh_b, bhh_f, bhh_b,
                                             h_f, h_b, enc, i);
    }

    // attention precompute + decoder input projection
    if (mf) {
        k_split<<<dim3(1, B_ * S_), 256, 0, stream>>>(enc, H_, H_ / 4, enc_h, enc_l);
        k_gemm_mfma3<<<dim3(16, H_ / 128), 256, 0, stream>>>(enc_h, enc_l, wae_h, wae_l,
                                                             ba, ep, H_, H_);
        k_gemm_mfma3<<<dim3(16, H3 / 128), 256, 0, stream>>>(demb_h, demb_l, wihd_h, wihd_l,
                                                             bih_d, gi_e, H3, E_);
    } else {
        k_gemm_nt<<<dim3(H_ / 128, (B_ * S_) / 128), 256, 0, stream>>>(
            enc, H_, Wa + H_, H2, ba, ep, H_, H_);
        k_gemm_nt<<<dim3(H3 / 128, (T_ * B_) / 128), 256, 0, stream>>>(
            dec_emb, E_, Wih_d, EH, bih_d, gi_e, H3, E_);
    }

    hipMemcpyAsync(h_d, h_f, (size_t)B_ * H_ * sizeof(float),
                   hipMemcpyDeviceToDevice, stream);

    // decoder: 64 sequential steps (logits deferred)
    for (int t = 0; t < 64; ++t) {
        k_gemm_rnn<<<dim3(H_ / 32, 1, 1), 256, 0, stream>>>(
            h_d, Wa, H2, hWa, nullptr, nullptr, 0, nullptr, H_);
        k_attn_scores<<<B_ * S_, 256, 0, stream>>>(hWa, ep, vv, scores);
        k_softmax_ctx<<<B_, 256, 0, stream>>>(scores, enc, ctx);
        k_gemm_rnn<<<dim3(H3 / 32, 1, 2), 256, 0, stream>>>(
            ctx, Wih_d + E_, EH, gic, h_d, Whh_d, H_, ghd, H3);
        k_dec_gates<<<128, 256, 0, stream>>>(gi_e, gic, ghd, bhh_d, ctx, h_d, states, t);
    }

    // output head: out = states @ Wout^T + bout, split-bf16 MFMA in 2 half-V passes
    if (mf) {
        k_split<<<dim3(2, T_ * B_), 256, 0, stream>>>(states, H2, H2 / 4, st_h, st_l);
        for (int p = 0; p < 2; ++p) {
            k_split<<<dim3(2, 16000), 256, 0, stream>>>(Wout + (size_t)p * 16000 * H2, H2,
                                                        H2 / 4, wout_h, wout_l);
            k_gemm_mfma3<<<dim3(16, 125), 256, 0, stream>>>(st_h, st_l, wout_h, wout_l,
                                                            bout + p * 16000,
                                                            out + (size_t)p * 16000, V_, H2);
        }
    } else {
        k_gemm_nt<<<dim3(V_ / 128, (T_ * B_) / 128), 256, 0, stream>>>(
            states, H2, Wout, H2, bout, out, V_, H2);
    }
}

// Round 3
// 8282.292 us; speedup vs baseline: 1.8711x; 1.4833x over previous
//
#include <hip/hip_runtime.h>
#include <hip/hip_bf16.h>

#define S_ 64
#define T_ 64
#define B_ 32
#define E_ 512
#define H_ 1024
#define V_ 32000
#define H3 3072
#define H2 2048
#define EH 1536

typedef unsigned short u16;
typedef unsigned int u32;
typedef __attribute__((ext_vector_type(8))) short bf16x8;
typedef __attribute__((ext_vector_type(4))) float f32x4;

#define MFMA3(ACC, AH_, AL_, BH_, BL_)                                              \
    ACC = __builtin_amdgcn_mfma_f32_16x16x32_bf16(AL_, BH_, ACC, 0, 0, 0);          \
    ACC = __builtin_amdgcn_mfma_f32_16x16x32_bf16(AH_, BL_, ACC, 0, 0, 0);          \
    ACC = __builtin_amdgcn_mfma_f32_16x16x32_bf16(AH_, BH_, ACC, 0, 0, 0);

__device__ __forceinline__ void splitf(float x, u16& h, u16& l) {
    u32 xb = __float_as_uint(x);
    u32 hb = (xb + 0x7FFFu + ((xb >> 16) & 1u)) & 0xFFFF0000u;  // RNE bf16 (as f32 bits)
    h = (u16)(hb >> 16);
    float lf = x - __uint_as_float(hb);                          // exact residual
    u32 lb = __float_as_uint(lf);
    l = (u16)((lb + 0x7FFFu + ((lb >> 16) & 1u)) >> 16);
}

__device__ __forceinline__ void load_lds16(const void* g, void* l) {
    __builtin_amdgcn_global_load_lds((const __attribute__((address_space(1))) u32*)g,
                                     (__attribute__((address_space(3))) u32*)l, 16, 0, 0);
}

// ---------------- embedding gather + split ----------------
__global__ void k_embed_src_split(const int* __restrict__ src, const float* __restrict__ emb,
                                  u16* __restrict__ hi, u16* __restrict__ lo) {
    int row = blockIdx.x;              // s*B + b
    int tok = src[row];
    int c = threadIdx.x * 4;           // 128 thr * 4 = 512
    float4 v = *reinterpret_cast<const float4*>(emb + (size_t)tok * E_ + c);
    ushort4 h, l;
    splitf(v.x, h.x, l.x); splitf(v.y, h.y, l.y);
    splitf(v.z, h.z, l.z); splitf(v.w, h.w, l.w);
    *reinterpret_cast<ushort4*>(hi + (size_t)row * E_ + c) = h;
    *reinterpret_cast<ushort4*>(lo + (size_t)row * E_ + c) = l;
}

__global__ void k_embed_dec_split(const int* __restrict__ src, const int* __restrict__ trg,
                                  const float* __restrict__ emb,
                                  u16* __restrict__ hi, u16* __restrict__ lo) {
    int row = blockIdx.x;              // t*B + b
    int t = row >> 5, b = row & 31;
    int tok = (t == 0) ? src[(S_ - 1) * B_ + b] : trg[(t - 1) * B_ + b];
    int c = threadIdx.x * 4;
    float4 v = *reinterpret_cast<const float4*>(emb + (size_t)tok * E_ + c);
    ushort4 h, l;
    splitf(v.x, h.x, l.x); splitf(v.y, h.y, l.y);
    splitf(v.z, h.z, l.z); splitf(v.w, h.w, l.w);
    *reinterpret_cast<ushort4*>(hi + (size_t)row * E_ + c) = h;
    *reinterpret_cast<ushort4*>(lo + (size_t)row * E_ + c) = l;
}

// ---------------- generic f32 -> bf16 hi/lo split: [rows][ld] -> [rows][cols4*4] ----------------
__global__ __launch_bounds__(256) void k_split(const float* __restrict__ in, int ld, int cols4,
                                               u16* __restrict__ hi, u16* __restrict__ lo) {
    int c4 = blockIdx.x * 256 + threadIdx.x;
    if (c4 >= cols4) return;
    size_t r = blockIdx.y;
    float4 v = *reinterpret_cast<const float4*>(in + r * ld + (size_t)c4 * 4);
    ushort4 h, l;
    splitf(v.x, h.x, l.x); splitf(v.y, h.y, l.y);
    splitf(v.z, h.z, l.z); splitf(v.w, h.w, l.w);
    size_t o = (r * cols4 + c4) * 4;
    *reinterpret_cast<ushort4*>(hi + o) = h;
    *reinterpret_cast<ushort4*>(lo + o) = l;
}

// ---------------- gate-interleaved weight split: dst row 3i+g = src row g*1024+i, 1024 cols ----------------
__global__ void k_wsplit_perm(const float* __restrict__ src, int ld, int coff,
                              u16* __restrict__ hi, u16* __restrict__ lo) {
    int r = blockIdx.x;                // permuted row: 3i+g
    int i = r / 3, g = r - i * 3;
    const float* p = src + (size_t)(g * H_ + i) * ld + coff;
    int c = threadIdx.x * 4;           // 256 thr * 4 = 1024
    float4 v = *reinterpret_cast<const float4*>(p + c);
    ushort4 h, l;
    splitf(v.x, h.x, l.x); splitf(v.y, h.y, l.y);
    splitf(v.z, h.z, l.z); splitf(v.w, h.w, l.w);
    *reinterpret_cast<ushort4*>(hi + (size_t)r * H_ + c) = h;
    *reinterpret_cast<ushort4*>(lo + (size_t)r * H_ + c) = l;
}

// ---------------- big split-bf16 MFMA GEMM (proven R2): C = Ah*Bh^T + Ah*Bl^T + Al*Bh^T + bias ----------------
__global__ __launch_bounds__(256, 2) void k_gemm_mfma3(
    const u16* __restrict__ Ah, const u16* __restrict__ Al,
    const u16* __restrict__ Bh, const u16* __restrict__ Bl,
    const float* __restrict__ bias, float* __restrict__ C,
    int ldc, int K)
{
    __shared__ u16 ls[4][128 * 32];
    const int tid = threadIdx.x;
    const int lane = tid & 63, w = tid >> 6;
    const int wr = w >> 1, wc = w & 1;
    const size_t m0 = (size_t)blockIdx.x * 128, n0 = (size_t)blockIdx.y * 128;

    const int c0 = (w * 2) * 64 + lane;
    const int r0 = c0 >> 2, kc0 = (c0 & 3) << 3;
    const size_t rstep = (size_t)16 * K;
    const u16* gAh = Ah + (m0 + r0) * K + kc0;
    const u16* gAl = Al + (m0 + r0) * K + kc0;
    const u16* gBh = Bh + (n0 + r0) * K + kc0;
    const u16* gBl = Bl + (n0 + r0) * K + kc0;
    const int lo0 = c0 * 8;

    const int frow = lane & 15, fk = (lane >> 4) << 3;
    const int offA = (wr * 64 + frow) * 32 + fk;
    const int offB = (wc * 64 + frow) * 32 + fk;

    f32x4 acc[4][4] = {};

    for (int k0 = 0; k0 < K; k0 += 32) {
        load_lds16(gAh + k0, &ls[0][lo0]);
        load_lds16(gAh + rstep + k0, &ls[0][lo0 + 512]);
        load_lds16(gAl + k0, &ls[1][lo0]);
        load_lds16(gAl + rstep + k0, &ls[1][lo0 + 512]);
        load_lds16(gBh + k0, &ls[2][lo0]);
        load_lds16(gBh + rstep + k0, &ls[2][lo0 + 512]);
        load_lds16(gBl + k0, &ls[3][lo0]);
        load_lds16(gBl + rstep + k0, &ls[3][lo0 + 512]);
        __syncthreads();

        bf16x8 fAh[4], fAl[4], fBh[4], fBl[4];
#pragma unroll
        for (int m = 0; m < 4; ++m) {
            fAh[m] = *reinterpret_cast<const bf16x8*>(&ls[0][offA + m * 512]);
            fAl[m] = *reinterpret_cast<const bf16x8*>(&ls[1][offA + m * 512]);
        }
#pragma unroll
        for (int n = 0; n < 4; ++n) {
            fBh[n] = *reinterpret_cast<const bf16x8*>(&ls[2][offB + n * 512]);
            fBl[n] = *reinterpret_cast<const bf16x8*>(&ls[3][offB + n * 512]);
        }
#pragma unroll
        for (int m = 0; m < 4; ++m)
#pragma unroll
            for (int n = 0; n < 4; ++n) {
                MFMA3(acc[m][n], fAh[m], fAl[m], fBh[n], fBl[n]);
            }
        __syncthreads();
    }

    const int crow0 = wr * 64 + ((lane >> 4) << 2);
    const int ccol0 = wc * 64 + (lane & 15);
#pragma unroll
    for (int n = 0; n < 4; ++n) {
        const size_t col = n0 + ccol0 + n * 16;
        const float bv = bias ? bias[col] : 0.f;
#pragma unroll
        for (int m = 0; m < 4; ++m)
#pragma unroll
            for (int r = 0; r < 4; ++r)
                C[(m0 + crow0 + m * 16 + r) * (size_t)ldc + col] = acc[m][n][r] + bv;
    }
}

// ============ fused encoder step: gh = h @ Whh_perm^T (MFMA) + GRU gates, both dirs ============
// grid 32: dir = x>>4, chunk = x&15 (chunk%8 -> stable XCD slice); i range = chunk*64..+63
__global__ __launch_bounds__(256) void k_enc_step(
    const u16* __restrict__ WfH, const u16* __restrict__ WfL,
    const u16* __restrict__ WbH, const u16* __restrict__ WbL,
    const u16* __restrict__ hfH, const u16* __restrict__ hfL,
    const u16* __restrict__ hbH, const u16* __restrict__ hbL,
    u16* __restrict__ ofH, u16* __restrict__ ofL,
    u16* __restrict__ obH, u16* __restrict__ obL,
    const float* __restrict__ hf_in, const float* __restrict__ hb_in,
    float* __restrict__ hf_out, float* __restrict__ hb_out,
    const float* __restrict__ gi_f, const float* __restrict__ gi_b,
    const float* __restrict__ bhh_f, const float* __restrict__ bhh_b,
    float* __restrict__ enc, int step)
{
    __shared__ __align__(16) char smem[28672];
    u16* lAh = (u16*)smem;                    // [32][32]
    u16* lAl = (u16*)(smem + 2048);
    u16* lBh = (u16*)(smem + 4096);           // [192][32]
    u16* lBl = (u16*)(smem + 16384);
    float* exch = (float*)smem;               // [192][33], aliased after K loop

    const int x = blockIdx.x;
    const int dir = x >> 4, chunk = x & 15;
    const int i0 = chunk * 64;
    const u16* WH = dir ? WbH : WfH;
    const u16* WL = dir ? WbL : WfL;
    const u16* AH = dir ? hbH : hfH;
    const u16* AL = dir ? hbL : hfL;
    const float* hin = dir ? hb_in : hf_in;
    float* hout = dir ? hb_out : hf_out;
    u16* oH = dir ? obH : ofH;
    u16* oL = dir ? obL : ofL;
    const float* gi = dir ? gi_b : gi_f;
    const float* bhh = dir ? bhh_b : bhh_f;
    const int s = dir ? 63 - step : step;

    const int tid = threadIdx.x, lane = tid & 63, w = tid >> 6;
    const int browbase = chunk * 192;         // permuted-row offset of this block
    const int cB = w * 64 + lane;
    const int cA = (w & 1) * 64 + lane;
    const int frow = lane & 15, fk8 = (lane >> 4) << 3;

    f32x4 acc[2][3] = {};

    for (int k0 = 0; k0 < 1024; k0 += 32) {
        {   // A stage: waves 0,1 -> hi; 2,3 -> lo (128 chunks each)
            const u16* Asrc = (w < 2) ? AH : AL;
            u16* Adst = (w < 2) ? lAh : lAl;
            int row = cA >> 2, k8 = (cA & 3) << 3;
            load_lds16(Asrc + (size_t)row * 1024 + k0 + k8, Adst + cA * 8);
        }
#pragma unroll
        for (int r = 0; r < 3; ++r) {         // B: 768 chunks per array
            int c = r * 256 + cB;
            int row = c >> 2, k8 = (c & 3) << 3;
            size_t go = (size_t)(browbase + row) * 1024 + k0 + k8;
            load_lds16(WH + go, lBh + c * 8);
            load_lds16(WL + go, lBl + c * 8);
        }
        __syncthreads();
        bf16x8 aH[2], aL[2], bH[3], bL[3];
#pragma unroll
        for (int mt = 0; mt < 2; ++mt) {
            aH[mt] = *(const bf16x8*)&lAh[(mt * 16 + frow) * 32 + fk8];
            aL[mt] = *(const bf16x8*)&lAl[(mt * 16 + frow) * 32 + fk8];
        }
#pragma unroll
        for (int nt = 0; nt < 3; ++nt) {
            int rl = (w * 3 + nt) * 16 + frow;
            bH[nt] = *(const bf16x8*)&lBh[rl * 32 + fk8];
            bL[nt] = *(const bf16x8*)&lBl[rl * 32 + fk8];
        }
#pragma unroll
        for (int mt = 0; mt < 2; ++mt)
#pragma unroll
            for (int nt = 0; nt < 3; ++nt) {
                MFMA3(acc[mt][nt], aH[mt], aL[mt], bH[nt], bL[nt]);
            }
        __syncthreads();
    }

    // exchange: exch[col within 192][b]
#pragma unroll
    for (int mt = 0; mt < 2; ++mt)
#pragma unroll
        for (int nt = 0; nt < 3; ++nt) {
            int c = (w * 3 + nt) * 16 + frow;
            int b = mt * 16 + ((lane >> 4) << 2);
#pragma unroll
            for (int r = 0; r < 4; ++r)
                exch[c * 33 + b + r] = acc[mt][nt][r];
        }
    __syncthreads();

    const int il = tid & 63;
    const int i = i0 + il;
#pragma unroll
    for (int q = 0; q < 8; ++q) {
        int b = (tid >> 6) * 8 + q;
        float ghr = exch[(3 * il + 0) * 33 + b] + bhh[i];
        float ghz = exch[(3 * il + 1) * 33 + b] + bhh[H_ + i];
        float ghn = exch[(3 * il + 2) * 33 + b] + bhh[2 * H_ + i];
        size_t gio = (size_t)(s * B_ + b) * H3 + i;
        float gir = gi[gio], giz = gi[gio + H_], gin = gi[gio + 2 * H_];
        float rr = 1.f / (1.f + expf(-(gir + ghr)));
        float zz = 1.f / (1.f + expf(-(giz + ghz)));
        float nn = tanhf(gin + rr * ghn);
        float hold = hin[b * H_ + i];
        float hnew = (1.f - zz) * nn + zz * hold;
        hout[b * H_ + i] = hnew;
        u16 hh, hl; splitf(hnew, hh, hl);
        oH[b * H_ + i] = hh; oL[b * H_ + i] = hl;
        enc[((size_t)b * 64 + s) * H_ + i] += hnew;
    }
}

// ============ decoder k1: outv[32][4096] = h @ Wcat^T (cols 0..1023 hWa natural; 1024+ = ghd permuted) ============
__global__ __launch_bounds__(256) void k_dec1(
    const u16* __restrict__ AH, const u16* __restrict__ AL,
    const u16* __restrict__ BH, const u16* __restrict__ BL,
    float* __restrict__ outv)
{
    __shared__ __align__(16) char smem[36864];
    u16* lAh = (u16*)smem;
    u16* lAl = (u16*)(smem + 2048);
    u16* lBh = (u16*)(smem + 4096);           // [256][32]
    u16* lBl = (u16*)(smem + 20480);

    const int n0 = blockIdx.x * 256;
    const int tid = threadIdx.x, lane = tid & 63, w = tid >> 6;
    const int cB = w * 64 + lane;
    const int cA = (w & 1) * 64 + lane;
    const int frow = lane & 15, fk8 = (lane >> 4) << 3;

    f32x4 acc[2][4] = {};

    for (int k0 = 0; k0 < 1024; k0 += 32) {
        {
            const u16* Asrc = (w < 2) ? AH : AL;
            u16* Adst = (w < 2) ? lAh : lAl;
            int row = cA >> 2, k8 = (cA & 3) << 3;
            load_lds16(Asrc + (size_t)row * 1024 + k0 + k8, Adst + cA * 8);
        }
#pragma unroll
        for (int r = 0; r < 4; ++r) {         // B: 1024 chunks per array
            int c = r * 256 + cB;
            int row = c >> 2, k8 = (c & 3) << 3;
            size_t go = (size_t)(n0 + row) * 1024 + k0 + k8;
            load_lds16(BH + go, lBh + c * 8);
            load_lds16(BL + go, lBl + c * 8);
        }
        __syncthreads();
        bf16x8 aH[2], aL[2], bH[4], bL[4];
#pragma unroll
        for (int mt = 0; mt < 2; ++mt) {
            aH[mt] = *(const bf16x8*)&lAh[(mt * 16 + frow) * 32 + fk8];
            aL[mt] = *(const bf16x8*)&lAl[(mt * 16 + frow) * 32 + fk8];
        }
#pragma unroll
        for (int nt = 0; nt < 4; ++nt) {
            int rl = (w * 4 + nt) * 16 + frow;
            bH[nt] = *(const bf16x8*)&lBh[rl * 32 + fk8];
            bL[nt] = *(const bf16x8*)&lBl[rl * 32 + fk8];
        }
#pragma unroll
        for (int mt = 0; mt < 2; ++mt)
#pragma unroll
            for (int nt = 0; nt < 4; ++nt) {
                MFMA3(acc[mt][nt], aH[mt], aL[mt], bH[nt], bL[nt]);
            }
        __syncthreads();
    }

#pragma unroll
    for (int mt = 0; mt < 2; ++mt)
#pragma unroll
        for (int nt = 0; nt < 4; ++nt) {
            int col = n0 + (w * 4 + nt) * 16 + (lane & 15);
            int b0 = mt * 16 + ((lane >> 4) << 2);
#pragma unroll
            for (int r = 0; r < 4; ++r)
                outv[(size_t)(b0 + r) * 4096 + col] = acc[mt][nt][r];
        }
}

// ============ decoder k2: fused attention (scores -> softmax -> ctx) + ctx split + states ctx-half ============
__global__ __launch_bounds__(256) void k_attn(
    const float* __restrict__ outv, const float* __restrict__ ep,
    const float* __restrict__ vv, const float* __restrict__ enc,
    u16* __restrict__ ctxh, u16* __restrict__ ctxl,
    float* __restrict__ states, int t)
{
    int b = blockIdx.x, tid = threadIdx.x;
    __shared__ float hv[1024], vs[1024], al[64];
    *(float4*)&hv[tid * 4] = *(const float4*)(outv + (size_t)b * 4096 + tid * 4);
    *(float4*)&vs[tid * 4] = *(const float4*)(vv + tid * 4);
    __syncthreads();
    int lane = tid & 63, w = tid >> 6;
    for (int ii = 0; ii < 16; ++ii) {
        int s = w * 16 + ii;
        const float* e = ep + ((size_t)b * 64 + s) * H_ + lane * 16;
        float acc = 0.f;
#pragma unroll
        for (int r = 0; r < 4; ++r) {
            float4 ev = *(const float4*)(e + r * 4);
            int k = lane * 16 + r * 4;
            acc += fmaxf(ev.x + hv[k + 0], 0.f) * vs[k + 0];
            acc += fmaxf(ev.y + hv[k + 1], 0.f) * vs[k + 1];
            acc += fmaxf(ev.z + hv[k + 2], 0.f) * vs[k + 2];
            acc += fmaxf(ev.w + hv[k + 3], 0.f) * vs[k + 3];
        }
        for (int off = 32; off; off >>= 1) acc += __shfl_down(acc, off);
        if (lane == 0) al[s] = acc;
    }
    __syncthreads();
    float ex = 0.f;
    if (tid < 64) {
        float m = -1e30f;
        for (int s2 = 0; s2 < 64; ++s2) m = fmaxf(m, al[s2]);
        float sum = 0.f;
        for (int s2 = 0; s2 < 64; ++s2) sum += expf(al[s2] - m);
        ex = expf(al[tid] - m) / sum;
    }
    __syncthreads();
    if (tid < 64) al[tid] = ex;
    __syncthreads();
    int j4 = tid * 4;
    float4 c = {0.f, 0.f, 0.f, 0.f};
    for (int s2 = 0; s2 < 64; ++s2) {
        float a = al[s2];
        float4 ev = *(const float4*)(enc + ((size_t)b * 64 + s2) * H_ + j4);
        c.x += a * ev.x; c.y += a * ev.y; c.z += a * ev.z; c.w += a * ev.w;
    }
    *(float4*)(states + ((size_t)t * B_ + b) * H2 + H_ + j4) = c;
    ushort4 ch, cl;
    splitf(c.x, ch.x, cl.x); splitf(c.y, ch.y, cl.y);
    splitf(c.z, ch.z, cl.z); splitf(c.w, ch.w, cl.w);
    *(ushort4*)(ctxh + b * H_ + j4) = ch;
    *(ushort4*)(ctxl + b * H_ + j4) = cl;
}

// ============ decoder k3: gic = ctx @ Wihdc_perm^T (MFMA) + GRU gates + state store ============
__global__ __launch_bounds__(256) void k_dec3(
    const u16* __restrict__ ctxH, const u16* __restrict__ ctxL,
    const u16* __restrict__ WH, const u16* __restrict__ WL,
    const float* __restrict__ outv, const float* __restrict__ gi_e,
    const float* __restrict__ bhh_d,
    const float* __restrict__ hin, float* __restrict__ hout,
    u16* __restrict__ oH, u16* __restrict__ oL,
    float* __restrict__ states, int t)
{
    __shared__ __align__(16) char smem[28672];
    u16* lAh = (u16*)smem;
    u16* lAl = (u16*)(smem + 2048);
    u16* lBh = (u16*)(smem + 4096);
    u16* lBl = (u16*)(smem + 16384);
    float* exch = (float*)smem;

    const int chunk = blockIdx.x;             // 16 blocks
    const int i0 = chunk * 64;
    const int tid = threadIdx.x, lane = tid & 63, w = tid >> 6;
    const int browbase = chunk * 192;
    const int cB = w * 64 + lane;
    const int cA = (w & 1) * 64 + lane;
    const int frow = lane & 15, fk8 = (lane >> 4) << 3;

    f32x4 acc[2][3] = {};

    for (int k0 = 0; k0 < 1024; k0 += 32) {
        {
            const u16* Asrc = (w < 2) ? ctxH : ctxL;
            u16* Adst = (w < 2) ? lAh : lAl;
            int row = cA >> 2, k8 = (cA & 3) << 3;
            load_lds16(Asrc + (size_t)row * 1024 + k0 + k8, Adst + cA * 8);
        }
#pragma unroll
        for (int r = 0; r < 3; ++r) {
            int c = r * 256 + cB;
            int row = c >> 2, k8 = (c & 3) << 3;
            size_t go = (size_t)(browbase + row) * 1024 + k0 + k8;
            load_lds16(WH + go, lBh + c * 8);
            load_lds16(WL + go, lBl + c * 8);
        }
        __syncthreads();
        bf16x8 aH[2], aL[2], bH[3], bL[3];
#pragma unroll
        for (int mt = 0; mt < 2; ++mt) {
            aH[mt] = *(const bf16x8*)&lAh[(mt * 16 + frow) * 32 + fk8];
            aL[mt] = *(const bf16x8*)&lAl[(mt * 16 + frow) * 32 + fk8];
        }
#pragma unroll
        for (int nt = 0; nt < 3; ++nt) {
            int rl = (w * 3 + nt) * 16 + frow;
            bH[nt] = *(const bf16x8*)&lBh[rl * 32 + fk8];
            bL[nt] = *(const bf16x8*)&lBl[rl * 32 + fk8];
        }
#pragma unroll
        for (int mt = 0; mt < 2; ++mt)
#pragma unroll
            for (int nt = 0; nt < 3; ++nt) {
                MFMA3(acc[mt][nt], aH[mt], aL[mt], bH[nt], bL[nt]);
            }
        __syncthreads();
    }

#pragma unroll
    for (int mt = 0; mt < 2; ++mt)
#pragma unroll
        for (int nt = 0; nt < 3; ++nt) {
            int c = (w * 3 + nt) * 16 + frow;
            int b = mt * 16 + ((lane >> 4) << 2);
#pragma unroll
            for (int r = 0; r < 4; ++r)
                exch[c * 33 + b + r] = acc[mt][nt][r];
        }
    __syncthreads();

    const int il = tid & 63;
    const int i = i0 + il;
#pragma unroll
    for (int q = 0; q < 8; ++q) {
        int b = (tid >> 6) * 8 + q;
        float gicr = exch[(3 * il + 0) * 33 + b];
        float gicz = exch[(3 * il + 1) * 33 + b];
        float gicn = exch[(3 * il + 2) * 33 + b];
        size_t gv = (size_t)b * 4096 + 1024 + 3 * (size_t)i;
        float ghr = outv[gv + 0] + bhh_d[i];
        float ghz = outv[gv + 1] + bhh_d[H_ + i];
        float ghn = outv[gv + 2] + bhh_d[2 * H_ + i];
        size_t gio = (size_t)(t * B_ + b) * H3 + i;
        float gir = gi_e[gio] + gicr;
        float giz = gi_e[gio + H_] + gicz;
        float gin = gi_e[gio + 2 * H_] + gicn;
        float rr = 1.f / (1.f + expf(-(gir + ghr)));
        float zz = 1.f / (1.f + expf(-(giz + ghz)));
        float nn = tanhf(gin + rr * ghn);
        float hold = hin[b * H_ + i];
        float hnew = (1.f - zz) * nn + zz * hold;
        hout[b * H_ + i] = hnew;
        u16 hh, hl; splitf(hnew, hh, hl);
        oH[b * H_ + i] = hh; oL[b * H_ + i] = hl;
        states[((size_t)t * B_ + b) * H2 + i] = hnew;
    }
}

extern "C" void kernel_launch(void* const* d_in, const int* in_sizes, int n_in,
                              void* d_out, int out_size, void* d_ws, size_t ws_size,
                              hipStream_t stream) {
    const int*   src   = (const int*)d_in[0];
    const int*   trg   = (const int*)d_in[1];
    const float* emb   = (const float*)d_in[2];
    const float* Wih_f = (const float*)d_in[3];
    const float* Whh_f = (const float*)d_in[4];
    const float* bih_f = (const float*)d_in[5];
    const float* bhh_f = (const float*)d_in[6];
    const float* Wih_b = (const float*)d_in[7];
    const float* Whh_b = (const float*)d_in[8];
    const float* bih_b = (const float*)d_in[9];
    const float* bhh_b = (const float*)d_in[10];
    const float* Wa    = (const float*)d_in[11];
    const float* ba    = (const float*)d_in[12];
    const float* vv    = (const float*)d_in[13];
    const float* Wih_d = (const float*)d_in[14];
    const float* Whh_d = (const float*)d_in[15];
    const float* bih_d = (const float*)d_in[16];
    const float* bhh_d = (const float*)d_in[17];
    const float* Wout  = (const float*)d_in[18];
    const float* bout  = (const float*)d_in[19];
    float* out = (float*)d_out;
    (void)in_sizes; (void)n_in; (void)out_size; (void)ws_size;

    float* w = (float*)d_ws;
    size_t o = 0;
    auto alloc = [&](size_t n) { float* p = w + o; o += n; return p; };
    float* gi_f = alloc((size_t)S_ * B_ * H3);       // encoder fwd gi; reused as gi_e
    float* gi_b = alloc((size_t)S_ * B_ * H3);       // encoder bwd gi; reused as states
    float* enc  = alloc((size_t)B_ * S_ * H_);
    float* ep   = alloc((size_t)B_ * S_ * H_);
    float* outv = alloc((size_t)B_ * 4096);
    float* hf32[2] = {alloc(B_ * H_), alloc(B_ * H_)};   // enc-fwd h, reused by decoder
    float* hb32[2] = {alloc(B_ * H_), alloc(B_ * H_)};
    float* gi_e   = gi_f;
    float* states = gi_b;

    u16* wu = (u16*)(w + o);
    size_t ou = 0;
    auto alloc16 = [&](size_t n) { u16* p = wu + ou; ou += n; return p; };
    u16* semb_h  = alloc16((size_t)S_ * B_ * E_);  u16* semb_l  = alloc16((size_t)S_ * B_ * E_);
    u16* demb_h  = alloc16((size_t)T_ * B_ * E_);  u16* demb_l  = alloc16((size_t)T_ * B_ * E_);
    u16* wihf_h  = alloc16((size_t)H3 * E_);       u16* wihf_l  = alloc16((size_t)H3 * E_);
    u16* wihb_h  = alloc16((size_t)H3 * E_);       u16* wihb_l  = alloc16((size_t)H3 * E_);
    u16* wihd_h  = alloc16((size_t)H3 * E_);       u16* wihd_l  = alloc16((size_t)H3 * E_);
    u16* wae_h   = alloc16((size_t)H_ * H_);       u16* wae_l   = alloc16((size_t)H_ * H_);
    u16* enc_h   = alloc16((size_t)B_ * S_ * H_);  u16* enc_l   = alloc16((size_t)B_ * S_ * H_);
    u16* st_h    = alloc16((size_t)T_ * B_ * H2);  u16* st_l    = alloc16((size_t)T_ * B_ * H2);
    u16* wout_h  = alloc16((size_t)6400 * H2);     u16* wout_l  = alloc16((size_t)6400 * H2);
    u16* whhf_h  = alloc16((size_t)H3 * H_);       u16* whhf_l  = alloc16((size_t)H3 * H_);   // permuted
    u16* whhb_h  = alloc16((size_t)H3 * H_);       u16* whhb_l  = alloc16((size_t)H3 * H_);   // permuted
    u16* wihdc_h = alloc16((size_t)H3 * H_);       u16* wihdc_l = alloc16((size_t)H3 * H_);   // permuted
    u16* wcat_h  = alloc16((size_t)4096 * H_);     u16* wcat_l  = alloc16((size_t)4096 * H_); // natural+perm
    u16* hsf_h[2] = {alloc16(B_ * H_), alloc16(B_ * H_)};
    u16* hsf_l[2] = {alloc16(B_ * H_), alloc16(B_ * H_)};
    u16* hsb_h[2] = {alloc16(B_ * H_), alloc16(B_ * H_)};
    u16* hsb_l[2] = {alloc16(B_ * H_), alloc16(B_ * H_)};
    u16* ctx_h   = alloc16(B_ * H_);               u16* ctx_l   = alloc16(B_ * H_);

    // ---- init ----
    hipMemsetAsync(enc, 0, (size_t)B_ * S_ * H_ * sizeof(float), stream);
    hipMemsetAsync(hf32[0], 0, B_ * H_ * sizeof(float), stream);
    hipMemsetAsync(hb32[0], 0, B_ * H_ * sizeof(float), stream);
    hipMemsetAsync(hsf_h[0], 0, B_ * H_ * sizeof(u16), stream);
    hipMemsetAsync(hsf_l[0], 0, B_ * H_ * sizeof(u16), stream);
    hipMemsetAsync(hsb_h[0], 0, B_ * H_ * sizeof(u16), stream);
    hipMemsetAsync(hsb_l[0], 0, B_ * H_ * sizeof(u16), stream);

    // ---- embeddings (gather + split) ----
    k_embed_src_split<<<S_ * B_, 128, 0, stream>>>(src, emb, semb_h, semb_l);
    k_embed_dec_split<<<T_ * B_, 128, 0, stream>>>(src, trg, emb, demb_h, demb_l);

    // ---- weight splits ----
    k_split<<<dim3(1, H3), 256, 0, stream>>>(Wih_f, E_, E_ / 4, wihf_h, wihf_l);
    k_split<<<dim3(1, H3), 256, 0, stream>>>(Wih_b, E_, E_ / 4, wihb_h, wihb_l);
    k_split<<<dim3(1, H3), 256, 0, stream>>>(Wih_d, EH, E_ / 4, wihd_h, wihd_l);        // emb part
    k_split<<<dim3(1, H_), 256, 0, stream>>>(Wa + H_, H2, H_ / 4, wae_h, wae_l);        // enc part
    k_split<<<dim3(1, H_), 256, 0, stream>>>(Wa, H2, H_ / 4, wcat_h, wcat_l);           // hWa rows (natural)
    k_wsplit_perm<<<H3, 256, 0, stream>>>(Whh_f, H_, 0, whhf_h, whhf_l);
    k_wsplit_perm<<<H3, 256, 0, stream>>>(Whh_b, H_, 0, whhb_h, whhb_l);
    k_wsplit_perm<<<H3, 256, 0, stream>>>(Wih_d, EH, E_, wihdc_h, wihdc_l);             // ctx part, permuted
    k_wsplit_perm<<<H3, 256, 0, stream>>>(Whh_d, H_, 0, wcat_h + (size_t)1024 * H_,
                                          wcat_l + (size_t)1024 * H_);                  // ghd rows, permuted

    // ---- encoder input projections (MFMA) ----
    k_gemm_mfma3<<<dim3(16, 24), 256, 0, stream>>>(semb_h, semb_l, wihf_h, wihf_l,
                                                   bih_f, gi_f, H3, E_);
    k_gemm_mfma3<<<dim3(16, 24), 256, 0, stream>>>(semb_h, semb_l, wihb_h, wihb_l,
                                                   bih_b, gi_b, H3, E_);

    // ---- encoder: 64 fused steps ----
    for (int i = 0; i < 64; ++i) {
        int a = i & 1;
        k_enc_step<<<32, 256, 0, stream>>>(
            whhf_h, whhf_l, whhb_h, whhb_l,
            hsf_h[a], hsf_l[a], hsb_h[a], hsb_l[a],
            hsf_h[1 - a], hsf_l[1 - a], hsb_h[1 - a], hsb_l[1 - a],
            hf32[a], hb32[a], hf32[1 - a], hb32[1 - a],
            gi_f, gi_b, bhh_f, bhh_b, enc, i);
    }
    // final fwd h: hf32[0] / hsf[0]  (64 steps end writing buffer 0)

    // ---- attention precompute ep + decoder emb projection ----
    k_split<<<dim3(1, B_ * S_), 256, 0, stream>>>(enc, H_, H_ / 4, enc_h, enc_l);
    k_gemm_mfma3<<<dim3(16, 8), 256, 0, stream>>>(enc_h, enc_l, wae_h, wae_l,
                                                  ba, ep, H_, H_);
    k_gemm_mfma3<<<dim3(16, 24), 256, 0, stream>>>(demb_h, demb_l, wihd_h, wihd_l,
                                                   bih_d, gi_e, H3, E_);

    // ---- decoder: 64 steps x 3 fused kernels (h buffers alias encoder-fwd buffers) ----
    for (int t = 0; t < 64; ++t) {
        int a = t & 1;
        k_dec1<<<16, 256, 0, stream>>>(hsf_h[a], hsf_l[a], wcat_h, wcat_l, outv);
        k_attn<<<B_, 256, 0, stream>>>(outv, ep, vv, enc, ctx_h, ctx_l, states, t);
        k_dec3<<<16, 256, 0, stream>>>(ctx_h, ctx_l, wihdc_h, wihdc_l, outv, gi_e,
                                       bhh_d, hf32[a], hf32[1 - a],
                                       hsf_h[1 - a], hsf_l[1 - a], states, t);
    }

    // ---- output head: out = states @ Wout^T + bout, 5 passes of 6400 vocab rows ----
    k_split<<<dim3(2, T_ * B_), 256, 0, stream>>>(states, H2, H2 / 4, st_h, st_l);
    for (int p = 0; p < 5; ++p) {
        k_split<<<dim3(2, 6400), 256, 0, stream>>>(Wout + (size_t)p * 6400 * H2, H2,
                                                   H2 / 4, wout_h, wout_l);
        k_gemm_mfma3<<<dim3(16, 50), 256, 0, stream>>>(st_h, st_l, wout_h, wout_l,
                                                       bout + p * 6400,
                                                       out + (size_t)p * 6400, V_, H2);
    }
}